// Round 4
// baseline (313.172 us; speedup 1.0000x reference)
//
#include <hip/hip_runtime.h>
#include <hip/hip_bf16.h>
#include <cstdint>
#include <cstddef>

// ---------------- problem constants ----------------
#define NHEADS 16
#define DHEAD  64
#define BATCH  2
#define SEQ    2048
#define DEMB   1024
#define TOK    (BATCH*SEQ)     // 4096 tokens
#define NQKV   (3*DEMB)        // 3072

typedef __bf16 bf16;
typedef __bf16 bf16x8 __attribute__((ext_vector_type(8)));
typedef __bf16 bf16x4 __attribute__((ext_vector_type(4)));
typedef float  f32x4  __attribute__((ext_vector_type(4)));

// async global->LDS, 16B per lane. LDS dest is wave-uniform base + lane*16.
static __device__ __forceinline__ void gload_lds16(const bf16* g, bf16* l) {
    __builtin_amdgcn_global_load_lds(
        (const __attribute__((address_space(1))) unsigned*)g,
        (__attribute__((address_space(3))) unsigned*)l, 16, 0, 0);
}

// ---------------- prepass: fp32 -> bf16 convert ----------------
__global__ __launch_bounds__(256) void cvt_bf16(const float* __restrict__ in,
                                                bf16* __restrict__ out, int n) {
    int i = (blockIdx.x * blockDim.x + threadIdx.x) * 4;
    if (i + 3 < n) {
        float4 v = *(const float4*)&in[i];
        bf16x4 o;
        o[0] = (bf16)v.x; o[1] = (bf16)v.y; o[2] = (bf16)v.z; o[3] = (bf16)v.w;
        *(bf16x4*)&out[i] = o;
    }
}

// in[R][C] fp32 -> out[C][R] bf16 (tiled transpose, +1 pad kills bank conflicts)
__global__ __launch_bounds__(256) void transpose_cvt(const float* __restrict__ in,
                                                     bf16* __restrict__ out,
                                                     int R, int C) {
    __shared__ float t[32][33];
    int c0 = blockIdx.x * 32, r0 = blockIdx.y * 32;
    int tx = threadIdx.x & 31, ty = threadIdx.x >> 5;   // 32 x 8
    #pragma unroll
    for (int i = 0; i < 32; i += 8)
        t[ty + i][tx] = in[(size_t)(r0 + ty + i) * C + c0 + tx];
    __syncthreads();
    #pragma unroll
    for (int i = 0; i < 32; i += 8)
        out[(size_t)(c0 + ty + i) * R + r0 + tx] = (bf16)t[tx][ty + i];
}

// ---------------- bf16 MFMA GEMM, C = A[M,K=1024] * Bt[N,K]^T + bias ----------------
// m97 structure: 128x128 tile, BK=32, 4 waves (2x2, 64x64 each), global_load_lds w16,
// XOR-swizzled LDS (chunk ^= (row>>1)&3 within 64B rows) so ds_read_b128 is 2-way max.
// mode 0: epilogue scatters QKV -> Qb[bh][s][d], Kb[bh][s][d], Vt[bh][d][s] (bf16)
// mode 1: epilogue writes fp32 Cout[M][1024]
#define BM 128
#define BN 128
#define BK 32

__global__ __launch_bounds__(256)
void gemm_bias(const bf16* __restrict__ A, const bf16* __restrict__ Bt,
               const float* __restrict__ bias, int mode,
               bf16* __restrict__ Qb, bf16* __restrict__ Kb,
               bf16* __restrict__ Vt, float* __restrict__ Cout) {
    __shared__ __align__(16) bf16 As[2][BM * BK];
    __shared__ __align__(16) bf16 Bs[2][BN * BK];
    const int K = 1024;
    const int tid = threadIdx.x;
    const int lane = tid & 63, wid = tid >> 6;
    const int gm0 = blockIdx.y * BM, gn0 = blockIdx.x * BN;
    const int wm = (wid >> 1) * 64, wn = (wid & 1) * 64;

    f32x4 acc[4][4];
    #pragma unroll
    for (int i = 0; i < 4; i++)
        #pragma unroll
        for (int j = 0; j < 4; j++)
            #pragma unroll
            for (int e = 0; e < 4; e++) acc[i][j][e] = 0.f;

    // fragment LDS offsets (elements), swizzled
    int a_off[4], b_off[4];
    #pragma unroll
    for (int f = 0; f < 4; f++) {
        int ra = wm + f * 16 + (lane & 15);
        a_off[f] = ra * BK + (((lane >> 4) ^ ((ra >> 1) & 3)) << 3);
        int rb = wn + f * 16 + (lane & 15);
        b_off[f] = rb * BK + (((lane >> 4) ^ ((rb >> 1) & 3)) << 3);
    }
    // staging source mapping: physical byte o = tid*16 + i*4096 -> (row, chunk)
    int srow[2], scol[2];
    #pragma unroll
    for (int i = 0; i < 2; i++) {
        int o = tid * 16 + i * 4096;
        int r = o >> 6;              // 64B per row (32 bf16)
        int c = (o >> 4) & 3;
        srow[i] = r;
        scol[i] = ((c ^ ((r >> 1) & 3)) << 3);  // inverse-swizzled global chunk
    }

    const int NKT = K / BK;  // 32
    int cur = 0;
    #pragma unroll
    for (int i = 0; i < 2; i++) {
        gload_lds16(&A[(size_t)(gm0 + srow[i]) * K + scol[i]],  &As[0][wid * 512 + i * 2048]);
        gload_lds16(&Bt[(size_t)(gn0 + srow[i]) * K + scol[i]], &Bs[0][wid * 512 + i * 2048]);
    }
    __syncthreads();
    for (int kt = 0; kt < NKT; ++kt) {
        if (kt + 1 < NKT) {
            int k0 = (kt + 1) * BK;
            #pragma unroll
            for (int i = 0; i < 2; i++) {
                gload_lds16(&A[(size_t)(gm0 + srow[i]) * K + k0 + scol[i]],
                            &As[cur ^ 1][wid * 512 + i * 2048]);
                gload_lds16(&Bt[(size_t)(gn0 + srow[i]) * K + k0 + scol[i]],
                            &Bs[cur ^ 1][wid * 512 + i * 2048]);
            }
        }
        bf16x8 af[4], bfr[4];
        #pragma unroll
        for (int f = 0; f < 4; f++) af[f]  = *(const bf16x8*)&As[cur][a_off[f]];
        #pragma unroll
        for (int f = 0; f < 4; f++) bfr[f] = *(const bf16x8*)&Bs[cur][b_off[f]];
        #pragma unroll
        for (int i = 0; i < 4; i++)
            #pragma unroll
            for (int j = 0; j < 4; j++)
                acc[i][j] = __builtin_amdgcn_mfma_f32_16x16x32_bf16(af[i], bfr[j], acc[i][j], 0, 0, 0);
        __syncthreads();
        cur ^= 1;
    }

    // epilogue: C/D layout col=lane&15, row=(lane>>4)*4+reg
    const int col_base = gn0 + wn + (lane & 15);
    const int row_base = gm0 + wm + ((lane >> 4) << 2);
    if (mode == 0) {
        #pragma unroll
        for (int j = 0; j < 4; j++) {
            int col = col_base + j * 16;
            float bv = bias[col];
            int sec = col >> 10;          // 0=Q 1=K 2=V (tiles never straddle: 128 | 1024)
            int within = col & 1023;
            int h = within >> 6, d = within & 63;
            #pragma unroll
            for (int i = 0; i < 4; i++)
                #pragma unroll
                for (int r = 0; r < 4; r++) {
                    int tok = row_base + i * 16 + r;
                    int b = tok >> 11, s = tok & 2047;
                    int bh = b * NHEADS + h;
                    bf16 v = (bf16)(acc[i][j][r] + bv);
                    if (sec == 0)      Qb[((size_t)bh * SEQ + s) * DHEAD + d] = v;
                    else if (sec == 1) Kb[((size_t)bh * SEQ + s) * DHEAD + d] = v;
                    else               Vt[((size_t)bh * DHEAD + d) * SEQ + s] = v;
                }
        }
    } else {
        #pragma unroll
        for (int j = 0; j < 4; j++) {
            int col = col_base + j * 16;
            float bv = bias[col];
            #pragma unroll
            for (int i = 0; i < 4; i++)
                #pragma unroll
                for (int r = 0; r < 4; r++) {
                    int tok = row_base + i * 16 + r;
                    Cout[(size_t)tok * DEMB + col] = acc[i][j][r] + bv;
                }
        }
    }
}

// ---------------- flash attention ----------------
// Flat 512-block grid, XCD-locality swizzle: under round-robin dispatch (bid%8),
// XCD k owns heads [4k,4k+4) -> each head's K/V (1MB) stays in that XCD's 4MB L2.
// 4 waves x 32 q-rows, waves independent (no block barrier). KV tiles of 64 read
// direct from global (L2-resident; m169: LDS-staging cache-fit data is overhead).
// Online softmax in exp2 units. P goes C-layout -> A-layout via per-wave swizzled LDS.
__global__ __launch_bounds__(256)
void attn_fwd(const bf16* __restrict__ Qb, const bf16* __restrict__ Kb,
              const bf16* __restrict__ Vt, bf16* __restrict__ attn_out) {
    __shared__ __align__(16) bf16 Pl[4][32 * 64];
    const int tid = threadIdx.x, lane = tid & 63, wid = tid >> 6;
    // bid -> (bh, qblk): xcd = bid&7 gets heads [xcd*4, xcd*4+4)
    const int bid = blockIdx.x;
    const int bh = (bid & 7) * 4 + ((bid >> 3) >> 4);
    const int q0 = ((bid >> 3) & 15) * 128 + wid * 32;
    const bf16* Qh = Qb + (size_t)bh * SEQ * DHEAD;
    const bf16* Kh = Kb + (size_t)bh * SEQ * DHEAD;
    const bf16* Vh = Vt + (size_t)bh * DHEAD * SEQ;
    bf16* Pw = &Pl[wid][0];

    // Q fragments live in registers for the whole kernel
    bf16x8 qf[2][2];
    #pragma unroll
    for (int mf = 0; mf < 2; mf++)
        #pragma unroll
        for (int kf = 0; kf < 2; kf++)
            qf[mf][kf] = *(const bf16x8*)&Qh[(size_t)(q0 + mf * 16 + (lane & 15)) * DHEAD
                                            + kf * 32 + ((lane >> 4) << 3)];

    f32x4 oacc[2][4];
    #pragma unroll
    for (int i = 0; i < 2; i++)
        #pragma unroll
        for (int j = 0; j < 4; j++)
            #pragma unroll
            for (int e = 0; e < 4; e++) oacc[i][j][e] = 0.f;
    float mrun[2][4], lrun[2][4];
    #pragma unroll
    for (int i = 0; i < 2; i++)
        #pragma unroll
        for (int r = 0; r < 4; r++) { mrun[i][r] = -INFINITY; lrun[i][r] = 0.f; }

    const float SC = 0.125f * 1.44269504088896f;  // 1/sqrt(64) * log2(e)

    for (int kv0 = 0; kv0 < SEQ; kv0 += 64) {
        // ---- S = Q @ K^T ----
        f32x4 sacc[2][4];
        #pragma unroll
        for (int i = 0; i < 2; i++)
            #pragma unroll
            for (int j = 0; j < 4; j++)
                #pragma unroll
                for (int e = 0; e < 4; e++) sacc[i][j][e] = 0.f;
        #pragma unroll
        for (int kf = 0; kf < 2; kf++) {
            bf16x8 kfr[4];
            #pragma unroll
            for (int nf = 0; nf < 4; nf++)
                kfr[nf] = *(const bf16x8*)&Kh[(size_t)(kv0 + nf * 16 + (lane & 15)) * DHEAD
                                              + kf * 32 + ((lane >> 4) << 3)];
            __builtin_amdgcn_s_setprio(1);
            #pragma unroll
            for (int mf = 0; mf < 2; mf++)
                #pragma unroll
                for (int nf = 0; nf < 4; nf++)
                    sacc[mf][nf] = __builtin_amdgcn_mfma_f32_16x16x32_bf16(qf[mf][kf], kfr[nf], sacc[mf][nf], 0, 0, 0);
            __builtin_amdgcn_s_setprio(0);
        }
        // ---- online softmax (exp2 units); rows spread over 16-lane groups ----
        #pragma unroll
        for (int mf = 0; mf < 2; mf++)
            #pragma unroll
            for (int r = 0; r < 4; r++) {
                float s0 = sacc[mf][0][r] * SC, s1 = sacc[mf][1][r] * SC;
                float s2 = sacc[mf][2][r] * SC, s3 = sacc[mf][3][r] * SC;
                float mx = fmaxf(fmaxf(s0, s1), fmaxf(s2, s3));
                mx = fmaxf(mx, __shfl_xor(mx, 1));
                mx = fmaxf(mx, __shfl_xor(mx, 2));
                mx = fmaxf(mx, __shfl_xor(mx, 4));
                mx = fmaxf(mx, __shfl_xor(mx, 8));
                float mnew = fmaxf(mrun[mf][r], mx);
                float corr = exp2f(mrun[mf][r] - mnew);
                float p0 = exp2f(s0 - mnew), p1 = exp2f(s1 - mnew);
                float p2 = exp2f(s2 - mnew), p3 = exp2f(s3 - mnew);
                float ps = p0 + p1 + p2 + p3;
                ps += __shfl_xor(ps, 1);
                ps += __shfl_xor(ps, 2);
                ps += __shfl_xor(ps, 4);
                ps += __shfl_xor(ps, 8);
                lrun[mf][r] = lrun[mf][r] * corr + ps;
                mrun[mf][r] = mnew;
                #pragma unroll
                for (int nf = 0; nf < 4; nf++) oacc[mf][nf][r] *= corr;
                sacc[mf][0][r] = p0; sacc[mf][1][r] = p1;
                sacc[mf][2][r] = p2; sacc[mf][3][r] = p3;
            }
        // ---- P: C-layout -> swizzled LDS (per-wave buffer, wave-synchronous) ----
        #pragma unroll
        for (int mf = 0; mf < 2; mf++)
            #pragma unroll
            for (int nf = 0; nf < 4; nf++)
                #pragma unroll
                for (int r = 0; r < 4; r++) {
                    int row = mf * 16 + ((lane >> 4) << 2) + r;
                    int col = nf * 16 + (lane & 15);
                    int addr = row * 64 + (((col >> 3) ^ (row & 7)) << 3) + (col & 7);
                    Pw[addr] = (bf16)sacc[mf][nf][r];
                }
        // ---- O += P @ V ----
        #pragma unroll
        for (int kf = 0; kf < 2; kf++) {
            bf16x8 pf[2], vf[4];
            #pragma unroll
            for (int mf = 0; mf < 2; mf++) {
                int row = mf * 16 + (lane & 15);
                int cc = kf * 4 + (lane >> 4);
                pf[mf] = *(const bf16x8*)&Pw[row * 64 + ((cc ^ (row & 7)) << 3)];
            }
            #pragma unroll
            for (int nf = 0; nf < 4; nf++)
                vf[nf] = *(const bf16x8*)&Vh[(size_t)(nf * 16 + (lane & 15)) * SEQ
                                             + kv0 + kf * 32 + ((lane >> 4) << 3)];
            __builtin_amdgcn_s_setprio(1);
            #pragma unroll
            for (int mf = 0; mf < 2; mf++)
                #pragma unroll
                for (int nf = 0; nf < 4; nf++)
                    oacc[mf][nf] = __builtin_amdgcn_mfma_f32_16x16x32_bf16(pf[mf], vf[nf], oacc[mf][nf], 0, 0, 0);
            __builtin_amdgcn_s_setprio(0);
        }
    }
    // ---- epilogue: O/l -> attn_out[b][s][h*64+d] (bf16, feeds out-proj GEMM) ----
    const int b = bh >> 4, h = bh & 15;
    #pragma unroll
    for (int mf = 0; mf < 2; mf++) {
        float inv[4];
        #pragma unroll
        for (int r = 0; r < 4; r++) inv[r] = 1.0f / lrun[mf][r];
        #pragma unroll
        for (int nf = 0; nf < 4; nf++)
            #pragma unroll
            for (int r = 0; r < 4; r++) {
                int s = q0 + mf * 16 + ((lane >> 4) << 2) + r;
                int d = nf * 16 + (lane & 15);
                attn_out[((size_t)b * SEQ + s) * DEMB + h * DHEAD + d] =
                    (bf16)(oacc[mf][nf][r] * inv[r]);
            }
    }
}

// ---------------- launch ----------------
extern "C" void kernel_launch(void* const* d_in, const int* in_sizes, int n_in,
                              void* d_out, int out_size, void* d_ws, size_t ws_size,
                              hipStream_t stream) {
    const float* x     = (const float*)d_in[0];
    const float* w_qkv = (const float*)d_in[1];
    const float* b_qkv = (const float*)d_in[2];
    const float* w_out = (const float*)d_in[3];
    const float* b_out = (const float*)d_in[4];
    float* out = (float*)d_out;

    // workspace layout (bf16 elements), ~40 MB total; attnO aliases xb
    // (x-bf16 is dead after the QKV GEMM).
    bf16* xb    = (bf16*)d_ws;                                   // [4096][1024]
    bf16* wqkvT = xb    + (size_t)TOK * DEMB;                    // [3072][1024]
    bf16* woutT = wqkvT + (size_t)NQKV * DEMB;                   // [1024][1024]
    bf16* Qb    = woutT + (size_t)DEMB * DEMB;                   // [32][2048][64]
    bf16* Kb    = Qb    + (size_t)BATCH * NHEADS * SEQ * DHEAD;
    bf16* Vt    = Kb    + (size_t)BATCH * NHEADS * SEQ * DHEAD;  // [32][64][2048]
    bf16* attnO = xb;                                            // alias: [4096][1024]

    cvt_bf16<<<(TOK * DEMB) / (256 * 4), 256, 0, stream>>>(x, xb, TOK * DEMB);
    transpose_cvt<<<dim3(NQKV / 32, DEMB / 32), 256, 0, stream>>>(w_qkv, wqkvT, DEMB, NQKV);
    transpose_cvt<<<dim3(DEMB / 32, DEMB / 32), 256, 0, stream>>>(w_out, woutT, DEMB, DEMB);
    gemm_bias<<<dim3(NQKV / BN, TOK / BM), 256, 0, stream>>>(xb, wqkvT, b_qkv, 0,
                                                             Qb, Kb, Vt, nullptr);
    attn_fwd<<<BATCH * NHEADS * (SEQ / 128), 256, 0, stream>>>(Qb, Kb, Vt, attnO);
    gemm_bias<<<dim3(DEMB / BN, TOK / BM), 256, 0, stream>>>(attnO, woutT, b_out, 1,
                                                             nullptr, nullptr, nullptr, out);
}

// Round 5
// 295.294 us; speedup vs baseline: 1.0605x; 1.0605x over previous
//
#include <hip/hip_runtime.h>
#include <hip/hip_bf16.h>
#include <cstdint>
#include <cstddef>

// ---------------- problem constants ----------------
#define NHEADS 16
#define DHEAD  64
#define BATCH  2
#define SEQ    2048
#define DEMB   1024
#define TOK    (BATCH*SEQ)     // 4096 tokens
#define NQKV   (3*DEMB)        // 3072

typedef __bf16 bf16;
typedef __bf16 bf16x8 __attribute__((ext_vector_type(8)));
typedef __bf16 bf16x4 __attribute__((ext_vector_type(4)));
typedef float  f32x4  __attribute__((ext_vector_type(4)));

// async global->LDS, 16B per lane. LDS dest is wave-uniform base + lane*16.
static __device__ __forceinline__ void gload_lds16(const bf16* g, bf16* l) {
    __builtin_amdgcn_global_load_lds(
        (const __attribute__((address_space(1))) unsigned*)g,
        (__attribute__((address_space(3))) unsigned*)l, 16, 0, 0);
}

// ---------------- prepass: fp32 -> bf16 convert ----------------
__global__ __launch_bounds__(256) void cvt_bf16(const float* __restrict__ in,
                                                bf16* __restrict__ out, int n) {
    int i = (blockIdx.x * blockDim.x + threadIdx.x) * 4;
    if (i + 3 < n) {
        float4 v = *(const float4*)&in[i];
        bf16x4 o;
        o[0] = (bf16)v.x; o[1] = (bf16)v.y; o[2] = (bf16)v.z; o[3] = (bf16)v.w;
        *(bf16x4*)&out[i] = o;
    }
}

// in[R][C] fp32 -> out[C][R] bf16 (tiled transpose, +1 pad kills bank conflicts)
__global__ __launch_bounds__(256) void transpose_cvt(const float* __restrict__ in,
                                                     bf16* __restrict__ out,
                                                     int R, int C) {
    __shared__ float t[32][33];
    int c0 = blockIdx.x * 32, r0 = blockIdx.y * 32;
    int tx = threadIdx.x & 31, ty = threadIdx.x >> 5;   // 32 x 8
    #pragma unroll
    for (int i = 0; i < 32; i += 8)
        t[ty + i][tx] = in[(size_t)(r0 + ty + i) * C + c0 + tx];
    __syncthreads();
    #pragma unroll
    for (int i = 0; i < 32; i += 8)
        out[(size_t)(c0 + ty + i) * R + r0 + tx] = (bf16)t[tx][ty + i];
}

// ---------------- bf16 MFMA GEMM, C = A[M,K=1024] * Bt[N,K]^T + bias ----------------
// m97 structure: 128x128 tile, BK=32, 4 waves (2x2, 64x64 each), global_load_lds w16,
// XOR-swizzled LDS (chunk ^= (row>>1)&3 within 64B rows) so ds_read_b128 is 2-way max.
// mode 0: epilogue scatters QKV -> Qb[bh][s][d] (Q PRE-SCALED by 1/8*log2e),
//         Kb[bh][s][d], Vt[bh][d][s] (bf16)
// mode 1: epilogue writes fp32 Cout[M][1024]
#define BM 128
#define BN 128
#define BK 32
#define QSC 0.180336880138855f   // (1/sqrt(64)) * log2(e)

__global__ __launch_bounds__(256)
void gemm_bias(const bf16* __restrict__ A, const bf16* __restrict__ Bt,
               const float* __restrict__ bias, int mode,
               bf16* __restrict__ Qb, bf16* __restrict__ Kb,
               bf16* __restrict__ Vt, float* __restrict__ Cout) {
    __shared__ __align__(16) bf16 As[2][BM * BK];
    __shared__ __align__(16) bf16 Bs[2][BN * BK];
    const int K = 1024;
    const int tid = threadIdx.x;
    const int lane = tid & 63, wid = tid >> 6;
    const int gm0 = blockIdx.y * BM, gn0 = blockIdx.x * BN;
    const int wm = (wid >> 1) * 64, wn = (wid & 1) * 64;

    f32x4 acc[4][4];
    #pragma unroll
    for (int i = 0; i < 4; i++)
        #pragma unroll
        for (int j = 0; j < 4; j++)
            #pragma unroll
            for (int e = 0; e < 4; e++) acc[i][j][e] = 0.f;

    // fragment LDS offsets (elements), swizzled
    int a_off[4], b_off[4];
    #pragma unroll
    for (int f = 0; f < 4; f++) {
        int ra = wm + f * 16 + (lane & 15);
        a_off[f] = ra * BK + (((lane >> 4) ^ ((ra >> 1) & 3)) << 3);
        int rb = wn + f * 16 + (lane & 15);
        b_off[f] = rb * BK + (((lane >> 4) ^ ((rb >> 1) & 3)) << 3);
    }
    // staging source mapping: physical byte o = tid*16 + i*4096 -> (row, chunk)
    int srow[2], scol[2];
    #pragma unroll
    for (int i = 0; i < 2; i++) {
        int o = tid * 16 + i * 4096;
        int r = o >> 6;              // 64B per row (32 bf16)
        int c = (o >> 4) & 3;
        srow[i] = r;
        scol[i] = ((c ^ ((r >> 1) & 3)) << 3);  // inverse-swizzled global chunk
    }

    const int NKT = K / BK;  // 32
    int cur = 0;
    #pragma unroll
    for (int i = 0; i < 2; i++) {
        gload_lds16(&A[(size_t)(gm0 + srow[i]) * K + scol[i]],  &As[0][wid * 512 + i * 2048]);
        gload_lds16(&Bt[(size_t)(gn0 + srow[i]) * K + scol[i]], &Bs[0][wid * 512 + i * 2048]);
    }
    __syncthreads();
    for (int kt = 0; kt < NKT; ++kt) {
        if (kt + 1 < NKT) {
            int k0 = (kt + 1) * BK;
            #pragma unroll
            for (int i = 0; i < 2; i++) {
                gload_lds16(&A[(size_t)(gm0 + srow[i]) * K + k0 + scol[i]],
                            &As[cur ^ 1][wid * 512 + i * 2048]);
                gload_lds16(&Bt[(size_t)(gn0 + srow[i]) * K + k0 + scol[i]],
                            &Bs[cur ^ 1][wid * 512 + i * 2048]);
            }
        }
        bf16x8 af[4], bfr[4];
        #pragma unroll
        for (int f = 0; f < 4; f++) af[f]  = *(const bf16x8*)&As[cur][a_off[f]];
        #pragma unroll
        for (int f = 0; f < 4; f++) bfr[f] = *(const bf16x8*)&Bs[cur][b_off[f]];
        #pragma unroll
        for (int i = 0; i < 4; i++)
            #pragma unroll
            for (int j = 0; j < 4; j++)
                acc[i][j] = __builtin_amdgcn_mfma_f32_16x16x32_bf16(af[i], bfr[j], acc[i][j], 0, 0, 0);
        __syncthreads();
        cur ^= 1;
    }

    // epilogue: C/D layout col=lane&15, row=(lane>>4)*4+reg
    const int col_base = gn0 + wn + (lane & 15);
    const int row_base = gm0 + wm + ((lane >> 4) << 2);
    if (mode == 0) {
        #pragma unroll
        for (int j = 0; j < 4; j++) {
            int col = col_base + j * 16;
            float bv = bias[col];
            int sec = col >> 10;          // 0=Q 1=K 2=V (tiles never straddle: 128 | 1024)
            int within = col & 1023;
            int h = within >> 6, d = within & 63;
            #pragma unroll
            for (int i = 0; i < 4; i++)
                #pragma unroll
                for (int r = 0; r < 4; r++) {
                    int tok = row_base + i * 16 + r;
                    int b = tok >> 11, s = tok & 2047;
                    int bh = b * NHEADS + h;
                    float fv = acc[i][j][r] + bv;
                    if (sec == 0)      Qb[((size_t)bh * SEQ + s) * DHEAD + d] = (bf16)(fv * QSC);
                    else if (sec == 1) Kb[((size_t)bh * SEQ + s) * DHEAD + d] = (bf16)fv;
                    else               Vt[((size_t)bh * DHEAD + d) * SEQ + s] = (bf16)fv;
                }
        }
    } else {
        #pragma unroll
        for (int j = 0; j < 4; j++) {
            int col = col_base + j * 16;
            float bv = bias[col];
            #pragma unroll
            for (int i = 0; i < 4; i++)
                #pragma unroll
                for (int r = 0; r < 4; r++) {
                    int tok = row_base + i * 16 + r;
                    Cout[(size_t)tok * DEMB + col] = acc[i][j][r] + bv;
                }
        }
    }
}

// ---------------- flash attention (swapped QK^T, in-register softmax) ----------------
// Flat 512-block grid, XCD-locality swizzle (bid&7 -> heads [4k,4k+4), K/V L2-resident).
// 4 independent waves x 32 q-rows. S^T = mfma(K_frag, Q_frag): identical loads to the
// unswapped form (A/B frags share the lane mapping), but each lane then owns one q-row
// (q = lane&15 per mf tile) -> row max/sum = 15 in-reg ops + 2 shfl_xor (vs 64 bpermute).
// Q arrives pre-scaled by 1/8*log2e, so S is already in exp2 units.
// Defer-max (THR=8): skip oacc rescale while the tile max grows < 2^8.
// P^T packs to bf16x4 -> 8x ds_write_b64 into the swizzled per-wave P buffer (PV unchanged).
__global__ __launch_bounds__(256)
void attn_fwd(const bf16* __restrict__ Qb, const bf16* __restrict__ Kb,
              const bf16* __restrict__ Vt, bf16* __restrict__ attn_out) {
    __shared__ __align__(16) bf16 Pl[4][32 * 64];
    const int tid = threadIdx.x, lane = tid & 63, wid = tid >> 6;
    const int g = lane >> 4;                 // 16-lane group 0..3
    const int bid = blockIdx.x;
    const int bh = (bid & 7) * 4 + ((bid >> 3) >> 4);
    const int q0 = ((bid >> 3) & 15) * 128 + wid * 32;
    const bf16* Qh = Qb + (size_t)bh * SEQ * DHEAD;
    const bf16* Kh = Kb + (size_t)bh * SEQ * DHEAD;
    const bf16* Vh = Vt + (size_t)bh * DHEAD * SEQ;
    bf16* Pw = &Pl[wid][0];

    // Q fragments live in registers for the whole kernel (pre-scaled)
    bf16x8 qf[2][2];
    #pragma unroll
    for (int mf = 0; mf < 2; mf++)
        #pragma unroll
        for (int kf = 0; kf < 2; kf++)
            qf[mf][kf] = *(const bf16x8*)&Qh[(size_t)(q0 + mf * 16 + (lane & 15)) * DHEAD
                                            + kf * 32 + (g << 3)];

    f32x4 oacc[2][4];
    #pragma unroll
    for (int i = 0; i < 2; i++)
        #pragma unroll
        for (int j = 0; j < 4; j++)
            #pragma unroll
            for (int e = 0; e < 4; e++) oacc[i][j][e] = 0.f;
    // running max / denom for q-row (lane&15) of each mf tile (softmax domain)
    float mrun[2] = {-INFINITY, -INFINITY};
    float lrun[2] = {0.f, 0.f};

    for (int kv0 = 0; kv0 < SEQ; kv0 += 64) {
        // ---- S^T = K @ Q^T (swapped operands; same frag loads) ----
        f32x4 sacc[2][4];
        #pragma unroll
        for (int i = 0; i < 2; i++)
            #pragma unroll
            for (int j = 0; j < 4; j++)
                #pragma unroll
                for (int e = 0; e < 4; e++) sacc[i][j][e] = 0.f;
        #pragma unroll
        for (int kf = 0; kf < 2; kf++) {
            bf16x8 kfr[4];
            #pragma unroll
            for (int nf = 0; nf < 4; nf++)
                kfr[nf] = *(const bf16x8*)&Kh[(size_t)(kv0 + nf * 16 + (lane & 15)) * DHEAD
                                              + kf * 32 + (g << 3)];
            __builtin_amdgcn_s_setprio(1);
            #pragma unroll
            for (int mf = 0; mf < 2; mf++)
                #pragma unroll
                for (int nf = 0; nf < 4; nf++)
                    sacc[mf][nf] = __builtin_amdgcn_mfma_f32_16x16x32_bf16(kfr[nf], qf[mf][kf], sacc[mf][nf], 0, 0, 0);
            __builtin_amdgcn_s_setprio(0);
        }
        // sacc[mf][nf][rr] = S^T[k = nf*16 + g*4 + rr][q = mf*16 + (lane&15)], exp2 units

        // ---- in-register online softmax over k (16 own values + cross-g) ----
        float mx[2];
        #pragma unroll
        for (int mf = 0; mf < 2; mf++) {
            float a = fmaxf(fmaxf(sacc[mf][0][0], sacc[mf][0][1]),
                            fmaxf(sacc[mf][0][2], sacc[mf][0][3]));
            float b = fmaxf(fmaxf(sacc[mf][1][0], sacc[mf][1][1]),
                            fmaxf(sacc[mf][1][2], sacc[mf][1][3]));
            float c = fmaxf(fmaxf(sacc[mf][2][0], sacc[mf][2][1]),
                            fmaxf(sacc[mf][2][2], sacc[mf][2][3]));
            float d = fmaxf(fmaxf(sacc[mf][3][0], sacc[mf][3][1]),
                            fmaxf(sacc[mf][3][2], sacc[mf][3][3]));
            float m = fmaxf(fmaxf(a, b), fmaxf(c, d));
            m = fmaxf(m, __shfl_xor(m, 16));
            m = fmaxf(m, __shfl_xor(m, 32));
            mx[mf] = m;
        }
        const bool defer = __all(fmaxf(mx[0] - mrun[0], mx[1] - mrun[1]) <= 8.0f);
        #pragma unroll
        for (int mf = 0; mf < 2; mf++) {
            float mnew = defer ? mrun[mf] : fmaxf(mrun[mf], mx[mf]);
            float corr = 1.0f;
            if (!defer) {
                corr = exp2f(mrun[mf] - mnew);
                // oacc rows are q = mf*16 + g*4 + rr; corr lives at lane (q&15)
                #pragma unroll
                for (int rr = 0; rr < 4; rr++) {
                    float c = __shfl(corr, (g << 2) + rr);
                    #pragma unroll
                    for (int nf = 0; nf < 4; nf++) oacc[mf][nf][rr] *= c;
                }
                mrun[mf] = mnew;
            }
            float psum = 0.f;
            #pragma unroll
            for (int nf = 0; nf < 4; nf++)
                #pragma unroll
                for (int rr = 0; rr < 4; rr++) {
                    float p = exp2f(sacc[mf][nf][rr] - mnew);
                    sacc[mf][nf][rr] = p;
                    psum += p;
                }
            psum += __shfl_xor(psum, 16);
            psum += __shfl_xor(psum, 32);
            lrun[mf] = lrun[mf] * corr + psum;
        }

        // ---- P^T -> packed bf16x4 -> swizzled LDS (row q, 4 consecutive k) ----
        #pragma unroll
        for (int mf = 0; mf < 2; mf++)
            #pragma unroll
            for (int nf = 0; nf < 4; nf++) {
                bf16x4 pk;
                #pragma unroll
                for (int rr = 0; rr < 4; rr++) pk[rr] = (bf16)sacc[mf][nf][rr];
                int q = mf * 16 + (lane & 15);
                int chunk = nf * 2 + (g >> 1);            // k>>3
                int addr = q * 64 + ((chunk ^ (q & 7)) << 3) + ((g & 1) << 2);
                *(bf16x4*)&Pw[addr] = pk;
            }

        // ---- O += P @ V (unchanged: A=P from LDS, B=V^T direct) ----
        #pragma unroll
        for (int kf = 0; kf < 2; kf++) {
            bf16x8 pf[2], vf[4];
            #pragma unroll
            for (int mf = 0; mf < 2; mf++) {
                int row = mf * 16 + (lane & 15);
                int cc = kf * 4 + g;
                pf[mf] = *(const bf16x8*)&Pw[row * 64 + ((cc ^ (row & 7)) << 3)];
            }
            #pragma unroll
            for (int nf = 0; nf < 4; nf++)
                vf[nf] = *(const bf16x8*)&Vh[(size_t)(nf * 16 + (lane & 15)) * SEQ
                                             + kv0 + kf * 32 + (g << 3)];
            __builtin_amdgcn_s_setprio(1);
            #pragma unroll
            for (int mf = 0; mf < 2; mf++)
                #pragma unroll
                for (int nf = 0; nf < 4; nf++)
                    oacc[mf][nf] = __builtin_amdgcn_mfma_f32_16x16x32_bf16(pf[mf], vf[nf], oacc[mf][nf], 0, 0, 0);
            __builtin_amdgcn_s_setprio(0);
        }
    }
    // ---- epilogue: O/l -> attn_out[b][s][h*64+d]; l lives at lane (q&15) ----
    const int b = bh >> 4, h = bh & 15;
    #pragma unroll
    for (int mf = 0; mf < 2; mf++) {
        float linv = 1.0f / lrun[mf];
        float linvr[4];
        #pragma unroll
        for (int rr = 0; rr < 4; rr++) linvr[rr] = __shfl(linv, (g << 2) + rr);
        #pragma unroll
        for (int nf = 0; nf < 4; nf++)
            #pragma unroll
            for (int rr = 0; rr < 4; rr++) {
                int s = q0 + mf * 16 + (g << 2) + rr;
                int d = nf * 16 + (lane & 15);
                attn_out[((size_t)b * SEQ + s) * DEMB + h * DHEAD + d] =
                    (bf16)(oacc[mf][nf][rr] * linvr[rr]);
            }
    }
}

// ---------------- launch ----------------
extern "C" void kernel_launch(void* const* d_in, const int* in_sizes, int n_in,
                              void* d_out, int out_size, void* d_ws, size_t ws_size,
                              hipStream_t stream) {
    const float* x     = (const float*)d_in[0];
    const float* w_qkv = (const float*)d_in[1];
    const float* b_qkv = (const float*)d_in[2];
    const float* w_out = (const float*)d_in[3];
    const float* b_out = (const float*)d_in[4];
    float* out = (float*)d_out;

    // workspace layout (bf16 elements), ~40 MB total; attnO aliases xb
    // (x-bf16 is dead after the QKV GEMM).
    bf16* xb    = (bf16*)d_ws;                                   // [4096][1024]
    bf16* wqkvT = xb    + (size_t)TOK * DEMB;                    // [3072][1024]
    bf16* woutT = wqkvT + (size_t)NQKV * DEMB;                   // [1024][1024]
    bf16* Qb    = woutT + (size_t)DEMB * DEMB;                   // [32][2048][64]
    bf16* Kb    = Qb    + (size_t)BATCH * NHEADS * SEQ * DHEAD;
    bf16* Vt    = Kb    + (size_t)BATCH * NHEADS * SEQ * DHEAD;  // [32][64][2048]
    bf16* attnO = xb;                                            // alias: [4096][1024]

    cvt_bf16<<<(TOK * DEMB) / (256 * 4), 256, 0, stream>>>(x, xb, TOK * DEMB);
    transpose_cvt<<<dim3(NQKV / 32, DEMB / 32), 256, 0, stream>>>(w_qkv, wqkvT, DEMB, NQKV);
    transpose_cvt<<<dim3(DEMB / 32, DEMB / 32), 256, 0, stream>>>(w_out, woutT, DEMB, DEMB);
    gemm_bias<<<dim3(NQKV / BN, TOK / BM), 256, 0, stream>>>(xb, wqkvT, b_qkv, 0,
                                                             Qb, Kb, Vt, nullptr);
    attn_fwd<<<BATCH * NHEADS * (SEQ / 128), 256, 0, stream>>>(Qb, Kb, Vt, attnO);
    gemm_bias<<<dim3(DEMB / BN, TOK / BM), 256, 0, stream>>>(attnO, woutT, b_out, 1,
                                                             nullptr, nullptr, nullptr, out);
}